// Round 7
// baseline (311.836 us; speedup 1.0000x reference)
//
#include <hip/hip_runtime.h>
#include <stdint.h>

typedef unsigned long long ull;

#define K_ANCH   8192
#define NCLS     91
#define NCC      90
#define B_SZ     8
#define CAP      1024          // per-(b,c) candidate capacity (mean ~330)
#define PRE_NMS  1000
#define MAXDET   100
#define CHUNK    64            // NMS mask-build chunk rows
#define NWMAX    16            // 1024/64 suppression-mask words
#define NBW      128           // bitmask words per (b,c) = 8192/64
#define SCORE_TH 0.05f
#define IOU_TH   0.5f
#define BBOX_CLIP 4.1351665565490723f   // float(log(1000/16))

__device__ __forceinline__ float wave_max64(float v) {
  #pragma unroll
  for (int off = 32; off > 0; off >>= 1) v = fmaxf(v, __shfl_xor(v, off, 64));
  return v;
}
__device__ __forceinline__ float wave_sum64(float v) {
  #pragma unroll
  for (int off = 32; off > 0; off >>= 1) v += __shfl_xor(v, off, 64);
  return v;
}

__device__ __forceinline__ float4 decode_clip(float4 e, float4 a, float imh, float imw) {
#pragma clang fp contract(off)
  float dy = e.x / 10.0f;
  float dx = e.y / 10.0f;
  float dh = fminf(e.z / 5.0f, BBOX_CLIP);
  float dw = fminf(e.w / 5.0f, BBOX_CLIP);
  float ah = a.z - a.x;
  float aw = a.w - a.y;
  float ayc = a.x + 0.5f * ah;
  float axc = a.y + 0.5f * aw;
  float yc = dy * ah + ayc;
  float xc = dx * aw + axc;
  float h = expf(dh) * ah;
  float w = expf(dw) * aw;
  float y1 = yc - 0.5f * h, x1 = xc - 0.5f * w;
  float y2 = yc + 0.5f * h, x2 = xc + 0.5f * w;
  y1 = fminf(fmaxf(y1, 0.0f), imh);
  x1 = fminf(fmaxf(x1, 0.0f), imw);
  y2 = fminf(fmaxf(y2, 0.0f), imh);
  x2 = fminf(fmaxf(x2, 0.0f), imw);
  return make_float4(y1, x1, y2, x2);
}

__device__ __forceinline__ bool iou_gt(float4 bi, float ai, float4 bj, float aj) {
#pragma clang fp contract(off)
  float iy1 = fmaxf(bi.x, bj.x);
  float ix1 = fmaxf(bi.y, bj.y);
  float iy2 = fminf(bi.z, bj.z);
  float ix2 = fminf(bi.w, bj.w);
  float inter = fmaxf(iy2 - iy1, 0.0f) * fmaxf(ix2 - ix1, 0.0f);
  float uni = ai + aj - inter;
  float iou = inter / (uni > 0.0f ? uni : 1.0f);
  return iou > IOU_TH;
}

// --- kT: softmax + bitmask + candidate staging {p, decoded box} per (b,c,word).
// 1024 thr = 16 waves x 4 rows; block covers 64 consecutive k = one bitmask word.
__global__ __launch_bounds__(1024) void kT_softmax(
    const float* __restrict__ raw_scores, const float* __restrict__ raw_boxes,
    const float4* __restrict__ anchors, const float* __restrict__ image_shape,
    float2* __restrict__ stats, ull* __restrict__ bmask,
    float* __restrict__ pstage, float4* __restrict__ bstage, int pcap)
{
  __shared__ ull    rowbits[64][2];   //  1 KB
  __shared__ float  sp[64][92];       // 23.5 KB probabilities
  __shared__ float4 sanch[64];        //  1 KB
  __shared__ int    wl[5760];         // 22.5 KB worklist
  __shared__ int    wl_n;
  int tid = threadIdx.x;
  int wv = tid >> 6, lane = tid & 63;
  int b = blockIdx.x >> 7;           // 128 blocks per batch
  int k0 = (blockIdx.x & 127) << 6;  // 64 rows per block
  if (tid == 0) wl_n = 0;
  if (tid < 64) sanch[tid] = anchors[(size_t)b * K_ANCH + k0 + tid];
  #pragma unroll
  for (int i = 0; i < 4; i++) {
    int rl = (wv << 2) + i;
    int row = b * K_ANCH + k0 + rl;
    const float* srow = raw_scores + (size_t)row * NCLS;
    float s0 = srow[lane];
    bool has1 = lane < (NCLS - 64);
    float s1 = has1 ? srow[64 + lane] : -INFINITY;
    float m = wave_max64(fmaxf(s0, s1));
    float e0 = expf(s0 - m);
    float e1 = has1 ? expf(s1 - m) : 0.0f;
    float denom = wave_sum64(e0 + e1);
    float p0 = e0 / denom;
    float p1 = e1 / denom;
    sp[rl][lane] = p0;
    if (has1) sp[rl][64 + lane] = p1;
    ull b0 = __ballot(lane >= 1 && p0 > SCORE_TH);
    ull b1 = __ballot(has1 && p1 > SCORE_TH);
    if (lane == 0) {
      stats[row] = make_float2(m, denom);
      rowbits[rl][0] = b0;
      rowbits[rl][1] = b1;
    }
  }
  __syncthreads();
  if (tid < NCC) {
    int c = tid + 1, w = c >> 6, bit = c & 63;
    ull out = 0;
    #pragma unroll
    for (int r = 0; r < 64; r++)
      out |= ((rowbits[r][w] >> bit) & 1ull) << r;
    bmask[(size_t)(b * NCC + tid) * NBW + (k0 >> 6)] = out;
    int cnt = __popcll(out);
    if (cnt > 0) {
      int basei = atomicAdd(&wl_n, cnt);
      ull m = out;
      int rank = 0;
      while (m) {
        int r = __ffsll(m) - 1;
        m &= m - 1;
        wl[basei + rank] = (c << 12) | (r << 6) | rank;   // c:7b, r:6b, rank:6b
        rank++;
      }
    }
  }
  __syncthreads();
  int nwl = wl_n;
  if (pcap > 0) {
    float imh = image_shape[b * 2 + 0];
    float imw = image_shape[b * 2 + 1];
    for (int t = tid; t < nwl; t += 1024) {
      int e = wl[t];
      int c = e >> 12, r = (e >> 6) & 63, rank = e & 63;
      if (rank >= pcap) continue;                 // kN slow path covers
      size_t row = (size_t)b * K_ANCH + k0 + r;
      float4 enc = ((const float4*)raw_boxes)[row * NCLS + c];
      float4 box = decode_clip(enc, sanch[r], imh, imw);
      size_t pw = (size_t)(b * NCC + (c - 1)) * NBW + (k0 >> 6);
      pstage[pw * pcap + rank] = sp[r][c];
      bstage[pw * pcap + rank] = box;
    }
  }
}

// --- kN: per-(b,c) staged-candidate assembly + hybrid sort + mask-NMS + output.
__global__ __launch_bounds__(256) void kN_nms(
    const float* __restrict__ raw_boxes, const float* __restrict__ raw_scores,
    const float4* __restrict__ anchors, const float* __restrict__ image_shape,
    const float2* __restrict__ stats, const ull* __restrict__ bmask,
    const float* __restrict__ pstage, const float4* __restrict__ bstage, int pcap,
    float* __restrict__ all_s, float4* __restrict__ all_b)
{
  __shared__ float4 sbox[PRE_NMS];          // 16 KB
  __shared__ float  sarea[PRE_NMS];         //  4 KB
  __shared__ float  sscore[PRE_NMS];        //  4 KB
  __shared__ ull    sbuf[1056];             // 8.45 KB: keys, then smask overlay
  __shared__ ull    sbm[NBW];               //  1 KB bitmask words
  __shared__ int    soff[NBW];
  __shared__ int    swtot[2];
  __shared__ int    s_n;
  __shared__ int    s_done;
#define SMASK(w, r) sbuf[(w) * (CHUNK + 1) + (r)]

  int bc  = blockIdx.x;
  int tid = threadIdx.x;
  int b = bc / NCC;
  int c = bc - b * NCC + 1;
  int outbase = bc * MAXDET;
  size_t rowb = (size_t)b * K_ANCH;

  // zero this (b,c)'s output region (ws is poisoned each launch)
  for (int i = tid; i < MAXDET; i += 256) {
    all_s[outbase + i] = 0.0f;
    all_b[outbase + i] = make_float4(0.f, 0.f, 0.f, 0.f);
  }

  // bitmask column -> popcounts -> parallel exclusive scan (2 waves)
  ull w0 = 0;
  int cnt = 0;
  if (tid < NBW) {
    w0 = bmask[(size_t)bc * NBW + tid];
    sbm[tid] = w0;
    cnt = __popcll(w0);
  }
  int incl = cnt;
  if (tid < 128) {
    int lane = tid & 63;
    #pragma unroll
    for (int d = 1; d < 64; d <<= 1) {
      int o = __shfl_up(incl, d, 64);
      if (lane >= d) incl += o;
    }
    if (lane == 63) swtot[tid >> 6] = incl;
  }
  if (tid == 0) s_done = 0;
  __syncthreads();
  if (tid < 128) soff[tid] = incl - cnt + ((tid >= 64) ? swtot[0] : 0);
  if (tid == 0) s_n = swtot[0] + swtot[1];
  __syncthreads();
  int n_load = min(s_n, CAP);

  // per-word: build sort keys from staged p (coalesced pstage reads)
  if (tid < NBW) {
    int slot = soff[tid];
    ull m = w0;
    int kb = tid << 6;
    int rank = 0;
    size_t pw = (size_t)bc * NBW + tid;
    while (m) {
      int bit = __ffsll(m) - 1;
      m &= m - 1;
      int k = kb + bit;
      float p;
      if (rank < pcap) {
        p = pstage[pw * (size_t)pcap + rank];
      } else {            // rare overflow: exact recompute
        size_t row = rowb + k;
        float s = raw_scores[row * NCLS + c];
        float2 md = stats[row];
        p = expf(s - md.x) / md.y;
      }
      if (slot < CAP)
        sbuf[slot] = ((ull)__float_as_uint(p) << 32) | (uint32_t)(K_ANCH - 1 - k);
      slot++;
      rank++;
    }
  }
  int n2 = (n_load <= 512) ? 512 : 1024;
  for (int i = n_load + tid; i < n2; i += 256) sbuf[i] = 0ull;
  __syncthreads();

  // sort desc by key = (score_bits<<32)|(8191-k)
  if (n_load <= 512) {
    // hybrid bitonic: 2 keys/thread in regs; shfl for strides<=32, LDS for 64/128
    ull e0 = sbuf[tid], e1 = sbuf[tid + 256];
    for (int size = 2; size <= 512; size <<= 1) {
      if (size == 512 && e0 < e1) { ull t = e0; e0 = e1; e1 = t; }   // stride 256
      for (int s = ((size >> 1) > 128 ? 128 : (size >> 1)); s >= 64; s >>= 1) {
        __syncthreads();
        sbuf[tid] = e0; sbuf[tid + 256] = e1;
        __syncthreads();
        ull p0 = sbuf[tid ^ s];
        ull p1 = sbuf[(tid + 256) ^ s];
        bool t0 = (((tid & s) == 0) == ((tid & size) == 0));
        bool t1 = ((((tid + 256) & s) == 0) == (((tid + 256) & size) == 0));
        e0 = t0 ? (e0 > p0 ? e0 : p0) : (e0 < p0 ? e0 : p0);
        e1 = t1 ? (e1 > p1 ? e1 : p1) : (e1 < p1 ? e1 : p1);
      }
      int smax = ((size >> 1) < 32 ? (size >> 1) : 32);
      for (int s = smax; s >= 1; s >>= 1) {
        ull p0 = __shfl_xor(e0, s, 64);
        ull p1 = __shfl_xor(e1, s, 64);
        bool t0 = (((tid & s) == 0) == ((tid & size) == 0));
        bool t1 = ((((tid + 256) & s) == 0) == (((tid + 256) & size) == 0));
        e0 = t0 ? (e0 > p0 ? e0 : p0) : (e0 < p0 ? e0 : p0);
        e1 = t1 ? (e1 > p1 ? e1 : p1) : (e1 < p1 ? e1 : p1);
      }
    }
    __syncthreads();
    sbuf[tid] = e0;
    sbuf[tid + 256] = e1;
    __syncthreads();
  } else {
    // generic in-LDS bitonic over 1024 (statistically never taken; correctness net)
    for (int size = 2; size <= 1024; size <<= 1) {
      for (int stride = size >> 1; stride > 0; stride >>= 1) {
        for (int i = tid; i < 1024; i += 256) {
          int j = i ^ stride;
          if (j > i) {
            ull ki = sbuf[i], kj = sbuf[j];
            bool desc = ((i & size) == 0);
            if (desc ? (ki < kj) : (ki > kj)) { sbuf[i] = kj; sbuf[j] = ki; }
          }
        }
        __syncthreads();
      }
    }
  }

  // fetch staged boxes for sorted survivors (32 KB-local region)
  int n_use = min(n_load, PRE_NMS);
  float imh = image_shape[b * 2 + 0];
  float imw = image_shape[b * 2 + 1];
  for (int i = tid; i < n_use; i += 256) {
    ull key = sbuf[i];
    int k = K_ANCH - 1 - (int)(key & 0xFFFFFFFFull);
    int w = k >> 6;
    int rank = __popcll(sbm[w] & ((1ull << (k & 63)) - 1ull));
    float4 box;
    if (rank < pcap) {
      box = bstage[((size_t)bc * NBW + w) * (size_t)pcap + rank];
    } else {            // rare overflow: exact recompute
      size_t row = rowb + k;
      float4 e = ((const float4*)raw_boxes)[row * NCLS + c];
      box = decode_clip(e, anchors[row], imh, imw);
    }
    sbox[i] = box;
    sscore[i] = __uint_as_float((uint32_t)(key >> 32));
    {
#pragma clang fp contract(off)
      sarea[i] = (box.z - box.x) * (box.w - box.y);
    }
  }

  // chunked mask NMS, early exit at 100 written. sbuf reused as smask.
  int nwords = (n_use + 63) >> 6;
  ull rem = 0;        // wave0 lane l (<16) holds removed-word l
  int written = 0;
  for (int c0 = 0; c0 < n_use; c0 += CHUNK) {
    __syncthreads();               // box fetch/prev-scan visible; sbuf overwritable
    if (s_done) break;             // uniform
    int nrows = min(CHUNK, n_use - c0);

    for (int p = tid; p < (nwords << 6); p += 256) {
      int w  = p >> 6;
      int rr = p & (CHUNK - 1);
      if (rr >= nrows) continue;
      int r = c0 + rr;
      float4 br = sbox[r];
      float  ar = sarea[r];
      int j0 = w << 6;
      int j1 = min(j0 + 64, n_use);
      int js = max(j0, r + 1);
      ull mrow = 0;
      for (int j = js; j < j1; j++) {
        if (iou_gt(br, ar, sbox[j], sarea[j])) mrow |= 1ull << (j - j0);
      }
      SMASK(w, rr) = mrow;
    }
    __syncthreads();               // build visible to wave 0

    if (tid < 64) {
      int lane = tid;
      for (int i = c0; i < c0 + nrows; i++) {
        int w = i >> 6, bit = i & 63;
        ull rw = __shfl(rem, w, 64);
        if (((rw >> bit) & 1ull) == 0) {         // alive
          if (lane < nwords) rem |= SMASK(lane, i - c0);
          int valid = 0;
          float4 bx;
          float sc = 0.f;
          if (lane == 0) {
            bx = sbox[i];
            valid = (bx.x > 0.f || bx.y > 0.f || bx.z > 0.f || bx.w > 0.f) ? 1 : 0;
            sc = sscore[i];
          }
          valid = __shfl(valid, 0, 64);
          if (valid) {
            if (lane == 0) {
              all_s[outbase + written] = sc;
              all_b[outbase + written] = bx;
            }
            written++;
            if (written == MAXDET) {
              if (lane == 0) s_done = 1;
              break;
            }
          }
        }
      }
    }
  }
#undef SMASK
}

// --- k3: 90-way merge of sorted per-class lists -> final top-100 per batch.
__global__ __launch_bounds__(256) void k3_final(
    const float* __restrict__ all_s, const float4* __restrict__ all_b,
    float* __restrict__ out)
{
  __shared__ float ss[NCC * MAXDET];   // 36 KB — all scores for this batch
  int b = blockIdx.x;
  int tid = threadIdx.x;
  const float* S = all_s + (size_t)b * NCC * MAXDET;
  for (int i = tid; i < NCC * MAXDET; i += 256) ss[i] = S[i];
  __syncthreads();
  if (tid >= 64) return;
  int lane = tid;

  float* fin_b = out;                          // (B,100,4)
  float* fin_s = out + B_SZ * MAXDET * 4;      // (B,100)
  float* fin_c = fin_s + B_SZ * MAXDET;        // (B,100)
  float* numo  = fin_c + B_SZ * MAXDET;        // (B,)

  int c0 = lane;           // class-slice 0..63
  int c1 = lane + 64;      // class-slice 64..89 (valid lane < 26)
  int p0 = 0, p1 = 0;
  // heads + 1-deep prefetch: LDS reload latency stays off the critical path
  ull cur0 = ((ull)__float_as_uint(ss[c0 * MAXDET]) << 32) | (uint32_t)(16383 - c0 * MAXDET);
  ull nxt0 = ((ull)__float_as_uint(ss[c0 * MAXDET + 1]) << 32) | (uint32_t)(16383 - (c0 * MAXDET + 1));
  ull cur1 = 0ull, nxt1 = 0ull;
  if (c1 < NCC) {
    cur1 = ((ull)__float_as_uint(ss[c1 * MAXDET]) << 32) | (uint32_t)(16383 - c1 * MAXDET);
    nxt1 = ((ull)__float_as_uint(ss[c1 * MAXDET + 1]) << 32) | (uint32_t)(16383 - (c1 * MAXDET + 1));
  }
  int cnt = 0;

  for (int step = 0; step < MAXDET; step++) {
    ull my = (cur0 > cur1) ? cur0 : cur1;
    ull g = my;
    #pragma unroll
    for (int off = 32; off > 0; off >>= 1) {
      ull o = __shfl_xor(g, off, 64);
      g = (o > g) ? o : g;
    }
    // advance the winning list (keys are unique)
    if (cur0 != 0ull && g == cur0) {
      p0++;
      cur0 = nxt0;
      int f = c0 * MAXDET + p0 + 1;
      nxt0 = (p0 + 1 < MAXDET)
           ? (((ull)__float_as_uint(ss[f]) << 32) | (uint32_t)(16383 - f)) : 0ull;
    } else if (cur1 != 0ull && g == cur1) {
      p1++;
      cur1 = nxt1;
      int f = c1 * MAXDET + p1 + 1;
      nxt1 = (p1 + 1 < MAXDET)
           ? (((ull)__float_as_uint(ss[f]) << 32) | (uint32_t)(16383 - f)) : 0ull;
    }

    if (lane == 0) {
      int flat = 16383 - (int)(g & 0xFFFFFFFFull);
      int cc = flat / MAXDET;
      float sc = __uint_as_float((uint32_t)(g >> 32));
      fin_s[b * MAXDET + step] = sc;
      fin_c[b * MAXDET + step] = (float)(cc + 1);
      float4 bx = all_b[(size_t)b * NCC * MAXDET + flat];
      ((float4*)fin_b)[b * MAXDET + step] = bx;
      if (sc > -1.0f) cnt++;
    }
  }
  if (lane == 0) numo[b] = (float)cnt;
}

extern "C" void kernel_launch(void* const* d_in, const int* in_sizes, int n_in,
                              void* d_out, int out_size, void* d_ws, size_t ws_size,
                              hipStream_t stream) {
  const float*  raw_boxes   = (const float*)d_in[0];
  const float*  raw_scores  = (const float*)d_in[1];
  const float4* anchors     = (const float4*)d_in[2];
  const float*  image_shape = (const float*)d_in[3];

  char* p = (char*)d_ws;
  size_t used = 0;
  auto alloc = [&](size_t bytes) {
    char* r = p + used;
    used += (bytes + 255) & ~(size_t)255;
    return r;
  };
  float2* stats = (float2*)alloc((size_t)B_SZ * K_ANCH * sizeof(float2));       // 512 KB
  ull*    bmask = (ull*)   alloc((size_t)B_SZ * NCC * NBW * sizeof(ull));       // 720 KB
  float*  all_s = (float*) alloc((size_t)B_SZ * NCC * MAXDET * sizeof(float));  // 288 KB
  float4* all_b = (float4*)alloc((size_t)B_SZ * NCC * MAXDET * sizeof(float4)); // 1.15 MB

  // staging capacity per (b,c,word): pick largest pcap in {16,8,4,2,1,0} that fits
  size_t nw = (size_t)B_SZ * NCC * NBW;   // 92160 words
  int pcap = 16;
  while (pcap > 0 && used + ((nw * pcap * 4 + 255) & ~(size_t)255)
                          + ((nw * pcap * 16 + 255) & ~(size_t)255) > ws_size)
    pcap >>= 1;
  float*  pstage = (float*) alloc(nw * (size_t)pcap * 4);
  float4* bstage = (float4*)alloc(nw * (size_t)pcap * 16);

  kT_softmax<<<B_SZ * 128, 1024, 0, stream>>>(raw_scores, raw_boxes, anchors, image_shape,
                                              stats, bmask, pstage, bstage, pcap);
  kN_nms<<<B_SZ * NCC, 256, 0, stream>>>(raw_boxes, raw_scores, anchors, image_shape,
                                         stats, bmask, pstage, bstage, pcap, all_s, all_b);
  k3_final<<<B_SZ, 256, 0, stream>>>(all_s, all_b, (float*)d_out);
}

// Round 8
// 277.536 us; speedup vs baseline: 1.1236x; 1.1236x over previous
//
#include <hip/hip_runtime.h>
#include <stdint.h>

typedef unsigned long long ull;

#define K_ANCH   8192
#define NCLS     91
#define NCC      90
#define B_SZ     8
#define CAP      1024          // per-(b,c) candidate capacity (mean ~330)
#define PRE_NMS  1000
#define MAXDET   100
#define NWMAX    16            // 1024/64 suppression words
#define NBW      128           // bitmask words per (b,c) = 8192/64
#define SCORE_TH 0.05f
#define IOU_TH   0.5f
#define BBOX_CLIP 4.1351665565490723f   // float(log(1000/16))

__device__ __forceinline__ float wave_max64(float v) {
  #pragma unroll
  for (int off = 32; off > 0; off >>= 1) v = fmaxf(v, __shfl_xor(v, off, 64));
  return v;
}
__device__ __forceinline__ float wave_sum64(float v) {
  #pragma unroll
  for (int off = 32; off > 0; off >>= 1) v += __shfl_xor(v, off, 64);
  return v;
}

__device__ __forceinline__ float4 decode_clip(float4 e, float4 a, float imh, float imw) {
#pragma clang fp contract(off)
  float dy = e.x / 10.0f;
  float dx = e.y / 10.0f;
  float dh = fminf(e.z / 5.0f, BBOX_CLIP);
  float dw = fminf(e.w / 5.0f, BBOX_CLIP);
  float ah = a.z - a.x;
  float aw = a.w - a.y;
  float ayc = a.x + 0.5f * ah;
  float axc = a.y + 0.5f * aw;
  float yc = dy * ah + ayc;
  float xc = dx * aw + axc;
  float h = expf(dh) * ah;
  float w = expf(dw) * aw;
  float y1 = yc - 0.5f * h, x1 = xc - 0.5f * w;
  float y2 = yc + 0.5f * h, x2 = xc + 0.5f * w;
  y1 = fminf(fmaxf(y1, 0.0f), imh);
  x1 = fminf(fmaxf(x1, 0.0f), imw);
  y2 = fminf(fmaxf(y2, 0.0f), imh);
  x2 = fminf(fmaxf(x2, 0.0f), imw);
  return make_float4(y1, x1, y2, x2);
}

__device__ __forceinline__ bool iou_gt(float4 bi, float ai, float4 bj, float aj) {
#pragma clang fp contract(off)
  float iy1 = fmaxf(bi.x, bj.x);
  float ix1 = fmaxf(bi.y, bj.y);
  float iy2 = fminf(bi.z, bj.z);
  float ix2 = fminf(bi.w, bj.w);
  float inter = fmaxf(iy2 - iy1, 0.0f) * fmaxf(ix2 - ix1, 0.0f);
  float uni = ai + aj - inter;
  float iou = inter / (uni > 0.0f ? uni : 1.0f);
  return iou > IOU_TH;
}

// --- kT: softmax + bitmask + candidate staging {p, decoded box} per (b,c,word).
// 1024 thr = 16 waves x 4 rows; block covers 64 consecutive k = one bitmask word.
__global__ __launch_bounds__(1024) void kT_softmax(
    const float* __restrict__ raw_scores, const float* __restrict__ raw_boxes,
    const float4* __restrict__ anchors, const float* __restrict__ image_shape,
    float2* __restrict__ stats, ull* __restrict__ bmask,
    float* __restrict__ pstage, float4* __restrict__ bstage, int pcap)
{
  __shared__ ull    rowbits[64][2];   //  1 KB
  __shared__ float  sp[64][92];       // 23.5 KB probabilities
  __shared__ float4 sanch[64];        //  1 KB
  __shared__ int    wl[5760];         // 22.5 KB worklist
  __shared__ int    wl_n;
  int tid = threadIdx.x;
  int wv = tid >> 6, lane = tid & 63;
  int b = blockIdx.x >> 7;           // 128 blocks per batch
  int k0 = (blockIdx.x & 127) << 6;  // 64 rows per block
  if (tid == 0) wl_n = 0;
  if (tid < 64) sanch[tid] = anchors[(size_t)b * K_ANCH + k0 + tid];
  #pragma unroll
  for (int i = 0; i < 4; i++) {
    int rl = (wv << 2) + i;
    int row = b * K_ANCH + k0 + rl;
    const float* srow = raw_scores + (size_t)row * NCLS;
    float s0 = srow[lane];
    bool has1 = lane < (NCLS - 64);
    float s1 = has1 ? srow[64 + lane] : -INFINITY;
    float m = wave_max64(fmaxf(s0, s1));
    float e0 = expf(s0 - m);
    float e1 = has1 ? expf(s1 - m) : 0.0f;
    float denom = wave_sum64(e0 + e1);
    float p0 = e0 / denom;
    float p1 = e1 / denom;
    sp[rl][lane] = p0;
    if (has1) sp[rl][64 + lane] = p1;
    ull b0 = __ballot(lane >= 1 && p0 > SCORE_TH);
    ull b1 = __ballot(has1 && p1 > SCORE_TH);
    if (lane == 0) {
      stats[row] = make_float2(m, denom);
      rowbits[rl][0] = b0;
      rowbits[rl][1] = b1;
    }
  }
  __syncthreads();
  if (tid < NCC) {
    int c = tid + 1, w = c >> 6, bit = c & 63;
    ull out = 0;
    #pragma unroll
    for (int r = 0; r < 64; r++)
      out |= ((rowbits[r][w] >> bit) & 1ull) << r;
    bmask[(size_t)(b * NCC + tid) * NBW + (k0 >> 6)] = out;
    int cnt = __popcll(out);
    if (cnt > 0) {
      int basei = atomicAdd(&wl_n, cnt);
      ull m = out;
      int rank = 0;
      while (m) {
        int r = __ffsll(m) - 1;
        m &= m - 1;
        wl[basei + rank] = (c << 12) | (r << 6) | rank;   // c:7b, r:6b, rank:6b
        rank++;
      }
    }
  }
  __syncthreads();
  int nwl = wl_n;
  if (pcap > 0) {
    float imh = image_shape[b * 2 + 0];
    float imw = image_shape[b * 2 + 1];
    for (int t = tid; t < nwl; t += 1024) {
      int e = wl[t];
      int c = e >> 12, r = (e >> 6) & 63, rank = e & 63;
      if (rank >= pcap) continue;                 // kN slow path covers
      size_t row = (size_t)b * K_ANCH + k0 + r;
      float4 enc = ((const float4*)raw_boxes)[row * NCLS + c];
      float4 box = decode_clip(enc, sanch[r], imh, imw);
      size_t pw = (size_t)(b * NCC + (c - 1)) * NBW + (k0 >> 6);
      pstage[pw * pcap + rank] = sp[r][c];
      bstage[pw * pcap + rank] = box;
    }
  }
}

// --- kN: staged-candidate assembly + hybrid sort + lazy column-block NMS.
__global__ __launch_bounds__(256) void kN_nms(
    const float* __restrict__ raw_boxes, const float* __restrict__ raw_scores,
    const float4* __restrict__ anchors, const float* __restrict__ image_shape,
    const float2* __restrict__ stats, const ull* __restrict__ bmask,
    const float* __restrict__ pstage, const float4* __restrict__ bstage, int pcap,
    float* __restrict__ all_s, float4* __restrict__ all_b)
{
  __shared__ float4 sbox[PRE_NMS];          // 16 KB
  __shared__ float  sarea[PRE_NMS];         //  4 KB
  __shared__ float  sscore[PRE_NMS];        //  4 KB
  __shared__ ull    sbuf[1056];             // 8.45 KB: sort keys, then M-column
  __shared__ ull    sbm[NBW];               //  1 KB bitmask words
  __shared__ ull    skw[NWMAX];             // kept-row bitmap
  __shared__ int    soff[NBW];
  __shared__ int    swtot[2];
  __shared__ int    s_n;
  __shared__ int    s_done;

  int bc  = blockIdx.x;
  int tid = threadIdx.x;
  int b = bc / NCC;
  int c = bc - b * NCC + 1;
  int outbase = bc * MAXDET;
  size_t rowb = (size_t)b * K_ANCH;

  // zero this (b,c)'s output region (ws is poisoned each launch)
  for (int i = tid; i < MAXDET; i += 256) {
    all_s[outbase + i] = 0.0f;
    all_b[outbase + i] = make_float4(0.f, 0.f, 0.f, 0.f);
  }
  if (tid < NWMAX) skw[tid] = 0ull;

  // bitmask column -> popcounts -> parallel exclusive scan (2 waves)
  ull w0 = 0;
  int cnt = 0;
  if (tid < NBW) {
    w0 = bmask[(size_t)bc * NBW + tid];
    sbm[tid] = w0;
    cnt = __popcll(w0);
  }
  int incl = cnt;
  if (tid < 128) {
    int lane = tid & 63;
    #pragma unroll
    for (int d = 1; d < 64; d <<= 1) {
      int o = __shfl_up(incl, d, 64);
      if (lane >= d) incl += o;
    }
    if (lane == 63) swtot[tid >> 6] = incl;
  }
  if (tid == 0) s_done = 0;
  __syncthreads();
  if (tid < 128) soff[tid] = incl - cnt + ((tid >= 64) ? swtot[0] : 0);
  if (tid == 0) s_n = swtot[0] + swtot[1];
  __syncthreads();
  int n_load = min(s_n, CAP);

  // per-word: build sort keys from staged p (coalesced pstage reads)
  if (tid < NBW) {
    int slot = soff[tid];
    ull m = w0;
    int kb = tid << 6;
    int rank = 0;
    size_t pw = (size_t)bc * NBW + tid;
    while (m) {
      int bit = __ffsll(m) - 1;
      m &= m - 1;
      int k = kb + bit;
      float p;
      if (rank < pcap) {
        p = pstage[pw * (size_t)pcap + rank];
      } else {            // rare overflow: exact recompute
        size_t row = rowb + k;
        float s = raw_scores[row * NCLS + c];
        float2 md = stats[row];
        p = expf(s - md.x) / md.y;
      }
      if (slot < CAP)
        sbuf[slot] = ((ull)__float_as_uint(p) << 32) | (uint32_t)(K_ANCH - 1 - k);
      slot++;
      rank++;
    }
  }
  int n2 = (n_load <= 512) ? 512 : 1024;
  for (int i = n_load + tid; i < n2; i += 256) sbuf[i] = 0ull;
  __syncthreads();

  // sort desc by key = (score_bits<<32)|(8191-k)
  if (n_load <= 512) {
    // hybrid bitonic: 2 keys/thread in regs; shfl for strides<=32, LDS for 64/128
    ull e0 = sbuf[tid], e1 = sbuf[tid + 256];
    for (int size = 2; size <= 512; size <<= 1) {
      if (size == 512 && e0 < e1) { ull t = e0; e0 = e1; e1 = t; }   // stride 256
      for (int s = ((size >> 1) > 128 ? 128 : (size >> 1)); s >= 64; s >>= 1) {
        __syncthreads();
        sbuf[tid] = e0; sbuf[tid + 256] = e1;
        __syncthreads();
        ull p0 = sbuf[tid ^ s];
        ull p1 = sbuf[(tid + 256) ^ s];
        bool t0 = (((tid & s) == 0) == ((tid & size) == 0));
        bool t1 = ((((tid + 256) & s) == 0) == (((tid + 256) & size) == 0));
        e0 = t0 ? (e0 > p0 ? e0 : p0) : (e0 < p0 ? e0 : p0);
        e1 = t1 ? (e1 > p1 ? e1 : p1) : (e1 < p1 ? e1 : p1);
      }
      int smax = ((size >> 1) < 32 ? (size >> 1) : 32);
      for (int s = smax; s >= 1; s >>= 1) {
        ull p0 = __shfl_xor(e0, s, 64);
        ull p1 = __shfl_xor(e1, s, 64);
        bool t0 = (((tid & s) == 0) == ((tid & size) == 0));
        bool t1 = ((((tid + 256) & s) == 0) == (((tid + 256) & size) == 0));
        e0 = t0 ? (e0 > p0 ? e0 : p0) : (e0 < p0 ? e0 : p0);
        e1 = t1 ? (e1 > p1 ? e1 : p1) : (e1 < p1 ? e1 : p1);
      }
    }
    __syncthreads();
    sbuf[tid] = e0;
    sbuf[tid + 256] = e1;
    __syncthreads();
  } else {
    // generic in-LDS bitonic over 1024 (statistically never taken; correctness net)
    for (int size = 2; size <= 1024; size <<= 1) {
      for (int stride = size >> 1; stride > 0; stride >>= 1) {
        for (int i = tid; i < 1024; i += 256) {
          int j = i ^ stride;
          if (j > i) {
            ull ki = sbuf[i], kj = sbuf[j];
            bool desc = ((i & size) == 0);
            if (desc ? (ki < kj) : (ki > kj)) { sbuf[i] = kj; sbuf[j] = ki; }
          }
        }
        __syncthreads();
      }
    }
  }

  // fetch staged boxes for sorted survivors (keys consumed here; sbuf freed after)
  int n_use = min(n_load, PRE_NMS);
  float imh = image_shape[b * 2 + 0];
  float imw = image_shape[b * 2 + 1];
  for (int i = tid; i < n_use; i += 256) {
    ull key = sbuf[i];
    int k = K_ANCH - 1 - (int)(key & 0xFFFFFFFFull);
    int w = k >> 6;
    int rank = __popcll(sbm[w] & ((1ull << (k & 63)) - 1ull));
    float4 box;
    if (rank < pcap) {
      box = bstage[((size_t)bc * NBW + w) * (size_t)pcap + rank];
    } else {            // rare overflow: exact recompute
      size_t row = rowb + k;
      float4 e = ((const float4*)raw_boxes)[row * NCLS + c];
      box = decode_clip(e, anchors[row], imh, imw);
    }
    sbox[i] = box;
    sscore[i] = __uint_as_float((uint32_t)(key >> 32));
    {
#pragma clang fp contract(off)
      sarea[i] = (box.z - box.x) * (box.w - box.y);
    }
  }

  // lazy column-block NMS: per chunk t, build ONLY column-word t (upper triangle,
  // kept earlier rows + current-chunk rows), then register-resident scan.
  int nwords_use = (n_use + 63) >> 6;
  int written = 0;
  for (int t = 0; t < nwords_use; t++) {
    __syncthreads();               // box fetch / prev chunk visible; sbuf reusable
    if (s_done) break;             // uniform
    int j0 = t << 6;
    int j1 = min(j0 + 64, n_use);
    int r_lim = j1;                // rows 0..r_lim-1 can affect this column

    for (int r = tid; r < r_lim; r += 256) {
      bool need = (r >= j0) || ((skw[r >> 6] >> (r & 63)) & 1ull);
      ull mrow = 0;
      if (need) {
        float4 br = sbox[r];
        float  ar = sarea[r];
        int js = max(j0, r + 1);
        for (int j = js; j < j1; j++)
          if (iou_gt(br, ar, sbox[j], sarea[j])) mrow |= 1ull << (j - j0);
      }
      sbuf[r] = mrow;
    }
    __syncthreads();               // column visible to wave 0

    if (tid < 64) {
      int lane = tid;
      // init supp with kept earlier rows' contributions (parallel OR-reduce)
      ull acc = 0;
      for (int r = lane; r < j0; r += 64)
        if ((skw[r >> 6] >> (r & 63)) & 1ull) acc |= sbuf[r];
      #pragma unroll
      for (int off = 32; off > 0; off >>= 1) acc |= __shfl_xor(acc, off, 64);
      ull supp = acc;
      // lane j holds row (j0+j)'s column word and validity
      ull mj = (j0 + lane < n_use) ? sbuf[j0 + lane] : 0ull;
      bool vj = false;
      float4 bl;
      if (j0 + lane < n_use) {
        bl = sbox[j0 + lane];
        vj = (bl.x > 0.f || bl.y > 0.f || bl.z > 0.f || bl.w > 0.f);
      }
      ull vball = __ballot(vj);
      ull keptw = 0;
      int nrows = j1 - j0;
      for (int j = 0; j < nrows; j++) {
        if (!((supp >> j) & 1ull)) {       // alive -> kept
          keptw |= 1ull << j;
          supp |= __shfl(mj, j, 64);
          if ((vball >> j) & 1ull) {
            if (lane == 0) {
              int i = j0 + j;
              all_s[outbase + written] = sscore[i];
              all_b[outbase + written] = sbox[i];
            }
            written++;
            if (written == MAXDET) {
              if (lane == 0) s_done = 1;
              break;
            }
          }
        }
      }
      if (lane == 0) skw[t] = keptw;
    }
  }
}

// --- k3: 90-way merge of sorted per-class lists -> final top-100 per batch.
__global__ __launch_bounds__(256) void k3_final(
    const float* __restrict__ all_s, const float4* __restrict__ all_b,
    float* __restrict__ out)
{
  __shared__ float ss[NCC * MAXDET];   // 36 KB — all scores for this batch
  int b = blockIdx.x;
  int tid = threadIdx.x;
  const float* S = all_s + (size_t)b * NCC * MAXDET;
  for (int i = tid; i < NCC * MAXDET; i += 256) ss[i] = S[i];
  __syncthreads();
  if (tid >= 64) return;
  int lane = tid;

  float* fin_b = out;                          // (B,100,4)
  float* fin_s = out + B_SZ * MAXDET * 4;      // (B,100)
  float* fin_c = fin_s + B_SZ * MAXDET;        // (B,100)
  float* numo  = fin_c + B_SZ * MAXDET;        // (B,)

  int c0 = lane;           // class-slice 0..63
  int c1 = lane + 64;      // class-slice 64..89 (valid lane < 26)
  int p0 = 0, p1 = 0;
  // heads + 1-deep prefetch: LDS reload latency stays off the critical path
  ull cur0 = ((ull)__float_as_uint(ss[c0 * MAXDET]) << 32) | (uint32_t)(16383 - c0 * MAXDET);
  ull nxt0 = ((ull)__float_as_uint(ss[c0 * MAXDET + 1]) << 32) | (uint32_t)(16383 - (c0 * MAXDET + 1));
  ull cur1 = 0ull, nxt1 = 0ull;
  if (c1 < NCC) {
    cur1 = ((ull)__float_as_uint(ss[c1 * MAXDET]) << 32) | (uint32_t)(16383 - c1 * MAXDET);
    nxt1 = ((ull)__float_as_uint(ss[c1 * MAXDET + 1]) << 32) | (uint32_t)(16383 - (c1 * MAXDET + 1));
  }
  int cnt = 0;

  for (int step = 0; step < MAXDET; step++) {
    ull my = (cur0 > cur1) ? cur0 : cur1;
    ull g = my;
    #pragma unroll
    for (int off = 32; off > 0; off >>= 1) {
      ull o = __shfl_xor(g, off, 64);
      g = (o > g) ? o : g;
    }
    // advance the winning list (keys are unique)
    if (cur0 != 0ull && g == cur0) {
      p0++;
      cur0 = nxt0;
      int f = c0 * MAXDET + p0 + 1;
      nxt0 = (p0 + 1 < MAXDET)
           ? (((ull)__float_as_uint(ss[f]) << 32) | (uint32_t)(16383 - f)) : 0ull;
    } else if (cur1 != 0ull && g == cur1) {
      p1++;
      cur1 = nxt1;
      int f = c1 * MAXDET + p1 + 1;
      nxt1 = (p1 + 1 < MAXDET)
           ? (((ull)__float_as_uint(ss[f]) << 32) | (uint32_t)(16383 - f)) : 0ull;
    }

    if (lane == 0) {
      int flat = 16383 - (int)(g & 0xFFFFFFFFull);
      int cc = flat / MAXDET;
      float sc = __uint_as_float((uint32_t)(g >> 32));
      fin_s[b * MAXDET + step] = sc;
      fin_c[b * MAXDET + step] = (float)(cc + 1);
      float4 bx = all_b[(size_t)b * NCC * MAXDET + flat];
      ((float4*)fin_b)[b * MAXDET + step] = bx;
      if (sc > -1.0f) cnt++;
    }
  }
  if (lane == 0) numo[b] = (float)cnt;
}

extern "C" void kernel_launch(void* const* d_in, const int* in_sizes, int n_in,
                              void* d_out, int out_size, void* d_ws, size_t ws_size,
                              hipStream_t stream) {
  const float*  raw_boxes   = (const float*)d_in[0];
  const float*  raw_scores  = (const float*)d_in[1];
  const float4* anchors     = (const float4*)d_in[2];
  const float*  image_shape = (const float*)d_in[3];

  char* p = (char*)d_ws;
  size_t used = 0;
  auto alloc = [&](size_t bytes) {
    char* r = p + used;
    used += (bytes + 255) & ~(size_t)255;
    return r;
  };
  float2* stats = (float2*)alloc((size_t)B_SZ * K_ANCH * sizeof(float2));       // 512 KB
  ull*    bmask = (ull*)   alloc((size_t)B_SZ * NCC * NBW * sizeof(ull));       // 720 KB
  float*  all_s = (float*) alloc((size_t)B_SZ * NCC * MAXDET * sizeof(float));  // 288 KB
  float4* all_b = (float4*)alloc((size_t)B_SZ * NCC * MAXDET * sizeof(float4)); // 1.15 MB

  // staging capacity per (b,c,word): pick largest pcap in {16,8,4,2,1,0} that fits
  size_t nw = (size_t)B_SZ * NCC * NBW;   // 92160 words
  int pcap = 16;
  while (pcap > 0 && used + ((nw * pcap * 4 + 255) & ~(size_t)255)
                          + ((nw * pcap * 16 + 255) & ~(size_t)255) > ws_size)
    pcap >>= 1;
  float*  pstage = (float*) alloc(nw * (size_t)pcap * 4);
  float4* bstage = (float4*)alloc(nw * (size_t)pcap * 16);

  kT_softmax<<<B_SZ * 128, 1024, 0, stream>>>(raw_scores, raw_boxes, anchors, image_shape,
                                              stats, bmask, pstage, bstage, pcap);
  kN_nms<<<B_SZ * NCC, 256, 0, stream>>>(raw_boxes, raw_scores, anchors, image_shape,
                                         stats, bmask, pstage, bstage, pcap, all_s, all_b);
  k3_final<<<B_SZ, 256, 0, stream>>>(all_s, all_b, (float*)d_out);
}